// Round 11
// baseline (302.418 us; speedup 1.0000x reference)
//
#include <hip/hip_runtime.h>
#include <hip/hip_fp16.h>
#include <math.h>

// T=1024 time steps, S=512 sequences, D=32 features, K=64 states (= wave width)
#define TT 1024
#define SS 512
#define DD 32
#define KK 64

#define LOG2PI_F 1.8378770664093453f

// Segmented forward recursion: NSEG segments of TT/NSEG emitted steps each;
// seg>0 burns in BURN steps from a flat init (contraction of the normalized
// recursion kills the init error; rounds 3-10 measured it below noise).
// NSEG=8: serial depth 192, 4096 waves = 4/SIMD. r10 measured per-wave issue
// ~194 cy/step at 44% SIMD issue occupancy with 2 waves -> 4 waves fit at
// ~78% issue and convert the measured ~250 cy/step latency stall into work.
#define NSEG 8
#define SEGLEN (TT / NSEG)   // 128
#define BURN 64

// Workspace layout (d_ws):
//   [0, 64MB)        : p''[T,S,K] fp16 (max-shifted emission probs)
//   [+0, +32KB)      : float mpart[8192] (per-wave sums of max log-emissions)
//   [+32KB, +16KB)   : float seq_logd[NSEG*S]
#define PBUF_BYTES ((size_t)TT * SS * KK * 2)
#define EM_WPB 4
#define EM_BLOCKS 2048
#define NWAVES (EM_BLOCKS * EM_WPB)   // 8192 waves, 64 items each = T*S

typedef float v2f __attribute__((ext_vector_type(2)));

__device__ __forceinline__ v2f fma2(v2f a, v2f b, v2f c) {
#if __has_builtin(__builtin_elementwise_fma)
    return __builtin_elementwise_fma(a, b, c);
#else
    v2f r; r.x = fmaf(a.x, b.x, c.x); r.y = fmaf(a.y, b.y, c.y); return r;
#endif
}

// ---------------------------------------------------------------------------
// DPP wave64 reductions: 6 VALU-latency ops (~50 cy serial). Result broadcast
// via readlane.
template <int CTRL, int RMASK>
__device__ __forceinline__ float dpp_add(float x) {
    int t = __builtin_amdgcn_update_dpp(0, __float_as_int(x), CTRL, RMASK, 0xf, true);
    return x + __int_as_float(t);
}
template <int CTRL, int RMASK>
__device__ __forceinline__ float dpp_max(float x) {
    int xi = __float_as_int(x);
    int t = __builtin_amdgcn_update_dpp(xi, xi, CTRL, RMASK, 0xf, false);
    return fmaxf(x, __int_as_float(t));
}
__device__ __forceinline__ float wave_reduce_sum(float x) {
    x = dpp_add<0x111, 0xf>(x);   // row_shr:1
    x = dpp_add<0x112, 0xf>(x);   // row_shr:2
    x = dpp_add<0x114, 0xf>(x);   // row_shr:4
    x = dpp_add<0x118, 0xf>(x);   // row_shr:8
    x = dpp_add<0x142, 0xa>(x);   // row_bcast:15 into rows 1,3
    x = dpp_add<0x143, 0xc>(x);   // row_bcast:31 into rows 2,3 -> lane63 total
    return __int_as_float(__builtin_amdgcn_readlane(__float_as_int(x), 63));
}
__device__ __forceinline__ float wave_reduce_max(float x) {
    x = dpp_max<0x111, 0xf>(x);
    x = dpp_max<0x112, 0xf>(x);
    x = dpp_max<0x114, 0xf>(x);
    x = dpp_max<0x118, 0xf>(x);
    x = dpp_max<0x142, 0xa>(x);
    x = dpp_max<0x143, 0xc>(x);
    return __int_as_float(__builtin_amdgcn_readlane(__float_as_int(x), 63));
}

// ---------------------------------------------------------------------------
// Emission: one wave per batch of 64 (t,s) items; lane = state k.
// p''[t,s,k] = exp(logp - max_k logp); mpart[wave] = sum of per-item maxes.
//
// r10 post-mortem: 2-item ILP got ~115us; residual is per-item chain latency,
// dominated by the 6-stage DPP-max (~70 cy serial) running once PER ITEM.
// This round batches each 8-item block into phases:
//   A) four 2-ILP quad-form pairs -> l0..l7 (named registers, no arrays);
//   B) EIGHT independent DPP-max chains back-to-back -- the scheduler
//      interleaves them (~1.2 chain latencies for all 8 instead of 8x);
//   C) 8 exp + 8 coalesced stores + macc.
// Transients ~120 regs, under the ~132 allocator ceiling (r8 rule: LDS
// x-staging keeps the long-lived set at w/m(64)+xr(4)).
__global__ __launch_bounds__(EM_WPB * 64)
__attribute__((amdgpu_waves_per_eu(1, 3)))
void emission_kernel(
    const float* __restrict__ data,      // [T,S,D]
    const float* __restrict__ means,     // [K,D]
    const float* __restrict__ covars,    // [K,D]
    __half* __restrict__ pbuf,           // [T,S,K]
    float* __restrict__ mpart)           // [NWAVES]
{
    const int k  = threadIdx.x & 63;
    const int w  = threadIdx.x >> 6;
    const int wv = blockIdx.x * EM_WPB + w;

    // Per-lane (state-k) emission constants: the ONLY long-lived registers.
    v2f w2[DD / 2], m2[DD / 2];
    float c0 = DD * LOG2PI_F;
#pragma unroll
    for (int d = 0; d < DD; ++d) {
        float c = covars[k * DD + d];
        ((float*)w2)[d] = 1.0f / c;
        ((float*)m2)[d] = means[k * DD + d];
        c0 += __logf(c);
    }

    // x staging: per wave, 2 buffers x 8 items x 32 floats (1 KB each).
    __shared__ __align__(16) float4 xst[EM_WPB][2][64];

    const int base = wv * 64;            // 64 consecutive items per wave
    const float4* dsrc = (const float4*)(data + (size_t)base * DD); // 512 f4

    // Prologue: stage item-block 0 (lane l -> float4 slot l, coalesced).
    float4 xr = dsrc[k];
    xst[w][0][k] = xr;
    __builtin_amdgcn_wave_barrier();

    float macc = 0.0f;
    int cur = 0;

    // Quad-form for items I and I+1 of the current block -> LA, LB.
#define QPAIR(I, LA, LB)                                                      \
    {                                                                         \
        const float4* x0q = (const float4*)(xb + (I) * DD);                   \
        const float4* x1q = (const float4*)(xb + ((I) + 1) * DD);             \
        v2f p00 = {0,0}, p01 = {0,0}, p10 = {0,0}, p11 = {0,0};               \
        _Pragma("unroll")                                                     \
        for (int d4 = 0; d4 < DD / 4; ++d4) {                                 \
            float4 x0 = x0q[d4];                                              \
            float4 x1 = x1q[d4];                                              \
            v2f xa0; xa0.x = x0.x; xa0.y = x0.y;                              \
            v2f xb0; xb0.x = x0.z; xb0.y = x0.w;                              \
            v2f xa1; xa1.x = x1.x; xa1.y = x1.y;                              \
            v2f xb1; xb1.x = x1.z; xb1.y = x1.w;                              \
            v2f ta0 = xa0 - m2[2 * d4],  tb0 = xb0 - m2[2 * d4 + 1];          \
            v2f ta1 = xa1 - m2[2 * d4],  tb1 = xb1 - m2[2 * d4 + 1];          \
            p00 = fma2(w2[2 * d4] * ta0, ta0, p00);                           \
            p01 = fma2(w2[2 * d4 + 1] * tb0, tb0, p01);                       \
            p10 = fma2(w2[2 * d4] * ta1, ta1, p10);                           \
            p11 = fma2(w2[2 * d4 + 1] * tb1, tb1, p11);                       \
        }                                                                     \
        v2f s0 = p00 + p01, s1 = p10 + p11;                                   \
        LA = -0.5f * ((s0.x + s0.y) + c0);                                    \
        LB = -0.5f * ((s1.x + s1.y) + c0);                                    \
    }

    for (int b = 0; b < 8; ++b) {        // 8 blocks of 8 items
        // Issue next block's load now (T14 issue-early; block 7 reloads
        // itself harmlessly instead of reading OOB).
        const int bn = (b + 1 < 8) ? (b + 1) : 7;
        xr = dsrc[bn * 64 + k];

        const float* xb = (const float*)&xst[w][cur][0];

        // Phase A: quad forms for all 8 items (2-ILP pairs).
        float l0, l1, l2, l3, l4, l5, l6, l7;
        QPAIR(0, l0, l1)
        QPAIR(2, l2, l3)
        QPAIR(4, l4, l5)
        QPAIR(6, l6, l7)

        // Phase B: 8 independent DPP-max chains (scheduler interleaves).
        float mx0 = wave_reduce_max(l0);
        float mx1 = wave_reduce_max(l1);
        float mx2 = wave_reduce_max(l2);
        float mx3 = wave_reduce_max(l3);
        float mx4 = wave_reduce_max(l4);
        float mx5 = wave_reduce_max(l5);
        float mx6 = wave_reduce_max(l6);
        float mx7 = wave_reduce_max(l7);

        // Phase C: exp + coalesced stores + macc.
        __half* pb = pbuf + (size_t)(base + b * 8) * KK + k;
        pb[0 * KK] = __float2half(__expf(l0 - mx0));
        pb[1 * KK] = __float2half(__expf(l1 - mx1));
        pb[2 * KK] = __float2half(__expf(l2 - mx2));
        pb[3 * KK] = __float2half(__expf(l3 - mx3));
        pb[4 * KK] = __float2half(__expf(l4 - mx4));
        pb[5 * KK] = __float2half(__expf(l5 - mx5));
        pb[6 * KK] = __float2half(__expf(l6 - mx6));
        pb[7 * KK] = __float2half(__expf(l7 - mx7));
        macc += ((mx0 + mx1) + (mx2 + mx3)) + ((mx4 + mx5) + (mx6 + mx7));

        // Write-late: the vmcnt wait lands here with 8 items of slack.
        xst[w][cur ^ 1][k] = xr;
        __builtin_amdgcn_wave_barrier();
        cur ^= 1;
    }
#undef QPAIR
    if (k == 0) mpart[wv] = macc;
}

// ---------------------------------------------------------------------------
// Sequential forward recursion, segmented. One wave per (sequence, segment);
// lane = state. Per-step code unchanged from the measured-best r10 build
// (88 VGPRs, no remat); only NSEG and the occupancy cap change.
//   seg0:   t in [0, 128), emits logd from t=0, init = initial[k]*p0.
//   seg>0:  t in [seg*128-64, (seg+1)*128): 64 burn-in steps from flat init
//           (normalized, logd NOT accumulated), then emits its 128 steps.
// amdgpu_waves_per_eu(1, 4): min=1 keeps the generous register budget
// (r8 rule); 4096 waves = 4/SIMD (88 VGPR x 4 = 352 <= 512).
// Normalize (DPP reduce + log) only every 4th step; t0 % 8 == 0 for all
// segments so the (t&3)==3 test folds at compile time in the unrolled body.
__global__ __launch_bounds__(64)
__attribute__((amdgpu_waves_per_eu(1, 4)))
void hmm_seq(
    const __half* __restrict__ pbuf,     // [T,S,K]
    const float* __restrict__ initial,   // [K]
    const float* __restrict__ trans,     // [K,K]
    float* __restrict__ out_alpha,       // [S,K]
    float* __restrict__ seq_logd)        // [NSEG*S]
{
    const int s   = blockIdx.x;
    const int seg = blockIdx.y;
    const int k   = threadIdx.x;

    const int emit_from = seg * SEGLEN;
    const int t0        = seg ? (emit_from - BURN) : 0;
    const int nsteps    = seg ? (SEGLEN + BURN) : SEGLEN;

    v2f acl[KK / 2];                     // pairs (A[2j][k], A[2j+1][k])
#pragma unroll
    for (int j = 0; j < KK / 2; ++j) {
        acl[j].x = trans[(2 * j) * KK + k];
        acl[j].y = trans[(2 * j + 1) * KK + k];
    }

    __shared__ __align__(16) float alpha_sh[KK];

    const __half* pp = pbuf + (size_t)s * KK + k;
    const size_t PST = (size_t)SS * KK;  // elements per time step

    __half pf[8];                        // 8-deep prefetch ring
#pragma unroll
    for (int i = 0; i < 8; ++i) pf[i] = pp[PST * (size_t)(t0 + i)];

    const float init_k = seg ? 1.0f : initial[k];
    float logd = 0.0f;
    float a = 0.0f;

    for (int mblk = 0; mblk < nsteps / 8; ++mblk) {
#pragma unroll
        for (int i = 0; i < 8; ++i) {
            const int t = t0 + 8 * mblk + i;
            const float pc = __half2float(pf[i]);
            int tn = t + 8; if (tn >= TT) tn = TT - 1;   // clamped (uniform)
            pf[i] = pp[PST * (size_t)tn];

            if (mblk == 0 && i == 0) {
                a = init_k * pc;
            } else {
                const float4* ash4 = (const float4*)alpha_sh;
                v2f a0 = {0,0}, a1 = {0,0}, a2 = {0,0}, a3 = {0,0};
#pragma unroll
                for (int j4 = 0; j4 < KK / 4; ++j4) {
                    float4 av = ash4[j4];
                    v2f lo; lo.x = av.x; lo.y = av.y;
                    v2f hi; hi.x = av.z; hi.y = av.w;
                    if (j4 & 1) {
                        a2 = fma2(lo, acl[2 * j4], a2);
                        a3 = fma2(hi, acl[2 * j4 + 1], a3);
                    } else {
                        a0 = fma2(lo, acl[2 * j4], a0);
                        a1 = fma2(hi, acl[2 * j4 + 1], a1);
                    }
                }
                v2f sv = (a0 + a1) + (a2 + a3);
                a = pc * (sv.x + sv.y);
            }

            if ((t & 3) == 3) {          // i==3 or i==7 (t0 % 8 == 0)
                float den = wave_reduce_sum(a);        // DPP, ~50 cy serial
                logd += (t >= emit_from) ? __logf(den) : 0.0f;
                a *= __builtin_amdgcn_rcpf(den);
            }

            alpha_sh[k] = a;
            __builtin_amdgcn_wave_barrier();   // order LDS write vs next reads
        }
    }

    if (seg == NSEG - 1) out_alpha[(size_t)s * KK + k] = a;  // t=1023 normalized
    if (k == 0) seq_logd[seg * SS + s] = logd;
}

// ---------------------------------------------------------------------------
// nll = -( sum seq_logd + sum mpart )
__global__ __launch_bounds__(256) void finalize(
    const float* __restrict__ seq_logd, const float* __restrict__ mpart,
    float* __restrict__ out_nll)
{
    float v = 0.0f;
    for (int j = threadIdx.x; j < NWAVES; j += 256) v += mpart[j];
    for (int j = threadIdx.x; j < NSEG * SS; j += 256) v += seq_logd[j];
#pragma unroll
    for (int off = 32; off > 0; off >>= 1)
        v += __shfl_xor(v, off, 64);
    __shared__ float sh[4];
    if ((threadIdx.x & 63) == 0) sh[threadIdx.x >> 6] = v;
    __syncthreads();
    if (threadIdx.x == 0) {
        double total = ((double)sh[0] + sh[1]) + ((double)sh[2] + sh[3]);
        out_nll[0] = (float)(-total);
    }
}

extern "C" void kernel_launch(void* const* d_in, const int* in_sizes, int n_in,
                              void* d_out, int out_size, void* d_ws, size_t ws_size,
                              hipStream_t stream) {
    const float* data    = (const float*)d_in[0];  // [T,S,D]
    const float* initial = (const float*)d_in[1];  // [K]
    const float* trans   = (const float*)d_in[2];  // [K,K]
    const float* means   = (const float*)d_in[3];  // [K,D]
    const float* covars  = (const float*)d_in[4];  // [K,D]

    float* out_alpha = (float*)d_out;                    // [S,K]
    float* out_nll   = (float*)d_out + (size_t)SS * KK;  // 1 float

    __half* pbuf     = (__half*)d_ws;
    float*  mpart    = (float*)((char*)d_ws + PBUF_BYTES);
    float*  seq_logd = (float*)((char*)d_ws + PBUF_BYTES + NWAVES * sizeof(float));

    emission_kernel<<<EM_BLOCKS, EM_WPB * 64, 0, stream>>>(
        data, means, covars, pbuf, mpart);
    hmm_seq<<<dim3(SS, NSEG), 64, 0, stream>>>(
        pbuf, initial, trans, out_alpha, seq_logd);
    finalize<<<1, 256, 0, stream>>>(seq_logd, mpart, out_nll);
}

// Round 12
// 287.601 us; speedup vs baseline: 1.0515x; 1.0515x over previous
//
#include <hip/hip_runtime.h>
#include <hip/hip_fp16.h>
#include <math.h>

// T=1024 time steps, S=512 sequences, D=32 features, K=64 states
#define TT 1024
#define SS 512
#define DD 32
#define KK 64

#define LOG2PI_F 1.8378770664093453f

// MFMA recursion: 16 sequences per wave; NSEG segments; seg>0 burns in BURN
// steps from a flat init (contraction kills the init error; validated r3-r11).
#define QSEQ 16
#define NSEG 16
#define SEGLEN (TT / NSEG)   // 64
#define BURN 64

// Workspace layout (d_ws):
//   [0, 64MB)        : p''[T,S,K] fp16 (max-shifted emission probs)
//   [+0, +32KB)      : float mpart[8192]
//   [+32KB, +32KB)   : float seq_logd[NSEG*S]
#define PBUF_BYTES ((size_t)TT * SS * KK * 2)
#define EM_WPB 4
#define EM_BLOCKS 2048
#define NWAVES (EM_BLOCKS * EM_WPB)   // 8192 waves, 64 items each = T*S

typedef float v2f __attribute__((ext_vector_type(2)));
typedef float f32x4 __attribute__((ext_vector_type(4)));
typedef _Float16 h8 __attribute__((ext_vector_type(8)));

__device__ __forceinline__ v2f fma2(v2f a, v2f b, v2f c) {
#if __has_builtin(__builtin_elementwise_fma)
    return __builtin_elementwise_fma(a, b, c);
#else
    v2f r; r.x = fmaf(a.x, b.x, c.x); r.y = fmaf(a.y, b.y, c.y); return r;
#endif
}

// ---------------------------------------------------------------------------
// DPP reductions.
template <int CTRL, int RMASK>
__device__ __forceinline__ float dpp_max(float x) {
    int xi = __float_as_int(x);
    int t = __builtin_amdgcn_update_dpp(xi, xi, CTRL, RMASK, 0xf, false);
    return fmaxf(x, __int_as_float(t));
}
__device__ __forceinline__ float wave_reduce_max(float x) {
    x = dpp_max<0x111, 0xf>(x);
    x = dpp_max<0x112, 0xf>(x);
    x = dpp_max<0x114, 0xf>(x);
    x = dpp_max<0x118, 0xf>(x);
    x = dpp_max<0x142, 0xa>(x);
    x = dpp_max<0x143, 0xc>(x);
    return __int_as_float(__builtin_amdgcn_readlane(__float_as_int(x), 63));
}
// 16-lane row sum via row_ror rotate-reduce: all 16 lanes end with the row
// total (4 DPP adds, no OOB semantics to worry about).
template <int N>
__device__ __forceinline__ float dpp_ror_add(float x) {
    int xi = __float_as_int(x);
    int t = __builtin_amdgcn_update_dpp(xi, xi, 0x120 + N, 0xf, 0xf, false);
    return x + __int_as_float(t);
}
__device__ __forceinline__ float rowsum16(float x) {
    x = dpp_ror_add<8>(x);
    x = dpp_ror_add<4>(x);
    x = dpp_ror_add<2>(x);
    x = dpp_ror_add<1>(x);
    return x;
}

// ---------------------------------------------------------------------------
// Emission (r10 measured-best: 2-item ILP, LDS x-staging, DPP max, (1,3)).
__global__ __launch_bounds__(EM_WPB * 64)
__attribute__((amdgpu_waves_per_eu(1, 3)))
void emission_kernel(
    const float* __restrict__ data,      // [T,S,D]
    const float* __restrict__ means,     // [K,D]
    const float* __restrict__ covars,    // [K,D]
    __half* __restrict__ pbuf,           // [T,S,K]
    float* __restrict__ mpart)           // [NWAVES]
{
    const int k  = threadIdx.x & 63;
    const int w  = threadIdx.x >> 6;
    const int wv = blockIdx.x * EM_WPB + w;

    v2f w2[DD / 2], m2[DD / 2];
    float c0 = DD * LOG2PI_F;
#pragma unroll
    for (int d = 0; d < DD; ++d) {
        float c = covars[k * DD + d];
        ((float*)w2)[d] = 1.0f / c;
        ((float*)m2)[d] = means[k * DD + d];
        c0 += __logf(c);
    }

    __shared__ __align__(16) float4 xst[EM_WPB][2][64];

    const int base = wv * 64;
    const float4* dsrc = (const float4*)(data + (size_t)base * DD);

    float4 xr = dsrc[k];
    xst[w][0][k] = xr;
    __builtin_amdgcn_wave_barrier();

    float macc = 0.0f;
    int cur = 0;

    for (int b = 0; b < 8; ++b) {
        const int bn = (b + 1 < 8) ? (b + 1) : 7;
        xr = dsrc[bn * 64 + k];

        const float* xb = (const float*)&xst[w][cur][0];
#pragma unroll
        for (int i = 0; i < 8; i += 2) {
            const float4* x0q = (const float4*)(xb + i * DD);
            const float4* x1q = (const float4*)(xb + (i + 1) * DD);
            v2f p00 = {0,0}, p01 = {0,0}, p10 = {0,0}, p11 = {0,0};
#pragma unroll
            for (int d4 = 0; d4 < DD / 4; ++d4) {
                float4 x0 = x0q[d4];
                float4 x1 = x1q[d4];
                v2f xa0; xa0.x = x0.x; xa0.y = x0.y;
                v2f xb0; xb0.x = x0.z; xb0.y = x0.w;
                v2f xa1; xa1.x = x1.x; xa1.y = x1.y;
                v2f xb1; xb1.x = x1.z; xb1.y = x1.w;
                v2f ta0 = xa0 - m2[2 * d4],  tb0 = xb0 - m2[2 * d4 + 1];
                v2f ta1 = xa1 - m2[2 * d4],  tb1 = xb1 - m2[2 * d4 + 1];
                p00 = fma2(w2[2 * d4] * ta0, ta0, p00);
                p01 = fma2(w2[2 * d4 + 1] * tb0, tb0, p01);
                p10 = fma2(w2[2 * d4] * ta1, ta1, p10);
                p11 = fma2(w2[2 * d4 + 1] * tb1, tb1, p11);
            }
            v2f s0 = p00 + p01, s1 = p10 + p11;
            float logp0 = -0.5f * ((s0.x + s0.y) + c0);
            float logp1 = -0.5f * ((s1.x + s1.y) + c0);
            float mx0 = wave_reduce_max(logp0);
            float mx1 = wave_reduce_max(logp1);
            const int item0 = base + b * 8 + i;
            pbuf[(size_t)item0 * KK + k]       = __float2half(__expf(logp0 - mx0));
            pbuf[(size_t)(item0 + 1) * KK + k] = __float2half(__expf(logp1 - mx1));
            macc += mx0 + mx1;
        }

        xst[w][cur ^ 1][k] = xr;
        __builtin_amdgcn_wave_barrier();
        cur ^= 1;
    }
    if (k == 0) mpart[wv] = macc;
}

// ---------------------------------------------------------------------------
// MFMA forward recursion: one wave = 16 sequences x one segment.
// alpha_new[16 seq x 64 k] = alpha[16 x 64] @ A[64 x 64] via 8x
// mfma_f32_16x16x32_f16 (4 N-tiles x 2 K-chunks), then pc-multiply,
// EVERY-step row-normalize (reference cadence; required for f16 alpha
// dynamic range), f16 transpose through LDS back to A-fragments.
// Layout contracts used:
//  - C/D: col(n) = lane&15, row(m) = (lane>>4)*4 + reg   [HW-verified]
//  - A: m = lane&15, k = (lane>>4)*8 + elem; B: n = lane&15, same k map.
//    (k-ordering cancels: both fragments built with the SAME map.)
// p staged via LDS in 4-step granules (issue-early/write-late, r7 mechanism).
#define RSTR 72   // padded LDS row stride in halfs (144 B: 16B-aligned, low conflict)

__global__ __launch_bounds__(64)
__attribute__((amdgpu_waves_per_eu(1, 1)))
void hmm_mfma(
    const __half* __restrict__ pbuf,     // [T,S,K] f16 max-shifted probs
    const float* __restrict__ initial,   // [K]
    const float* __restrict__ trans,     // [K,K]
    float* __restrict__ out_alpha,       // [S,K]
    float* __restrict__ seq_logd)        // [NSEG*S]
{
    const int lane = threadIdx.x;
    const int col  = lane & 15;          // n / k_out-within-tile; A-read row m
    const int grp  = lane >> 4;          // 0..3
    const int s0   = blockIdx.x * QSEQ;
    const int seg  = blockIdx.y;

    const int emit_from = seg * SEGLEN;
    const int t0        = seg ? (emit_from - BURN) : 0;
    const int nsteps    = seg ? (SEGLEN + BURN) : SEGLEN;   // 128 / 64

    // B fragments: A_hmm[j][k_out] as f16, tile (kc,nt); elem e <-> j =
    // kc*32 + grp*8 + e  (same k-map as the A-fragment reads below).
    h8 bf[2][4];
#pragma unroll
    for (int kc = 0; kc < 2; ++kc)
#pragma unroll
        for (int nt = 0; nt < 4; ++nt) {
            h8 v;
#pragma unroll
            for (int e = 0; e < 8; ++e) {
                int j = kc * 32 + grp * 8 + e;
                v[e] = (_Float16)trans[j * KK + nt * 16 + col];
            }
            bf[kc][nt] = v;
        }

    float init_c[4];
#pragma unroll
    for (int nt = 0; nt < 4; ++nt)
        init_c[nt] = seg ? 1.0f : initial[nt * 16 + col];

    // LDS: alpha transpose buffer + double-buffered 4-step p staging.
    __shared__ __align__(16) _Float16 ash[QSEQ * RSTR];          // 2.3 KB
    __shared__ __align__(16) _Float16 plds[2][4 * QSEQ * RSTR];  // 18.4 KB

    // p staging: lane <-> (step-in-granule = grp, seq = col); one 128B row.
    float4 pr[8];
#define XLOAD(TB)                                                             \
    {                                                                         \
        const float4* src = (const float4*)(pbuf +                            \
            (((size_t)((TB) + grp)) * SS + s0 + col) * KK);                   \
        _Pragma("unroll")                                                     \
        for (int e = 0; e < 8; ++e) pr[e] = src[e];                           \
    }
#define XWRITE(BUF)                                                           \
    {                                                                         \
        float4* dst = (float4*)(&plds[BUF][(grp * 16 + col) * RSTR]);         \
        _Pragma("unroll")                                                     \
        for (int e = 0; e < 8; ++e) dst[e] = pr[e];                           \
    }

    XLOAD(t0);
    XWRITE(0);
    __builtin_amdgcn_wave_barrier();

    h8 a0, a1;                 // current alpha A-fragments (kc = 0, 1)
    float ld[4] = {0.0f, 0.0f, 0.0f, 0.0f};   // logd per local seq j
    int cur = 0;

    for (int g = 0; g < nsteps / 4; ++g) {
        const int tbase = t0 + 4 * g;
        int tb_next = tbase + 4;
        if (tb_next > TT - 4) tb_next = TT - 4;   // uniform clamp (harmless)
        XLOAD(tb_next);

        const _Float16* pc_base = &plds[cur][0];
#pragma unroll
        for (int st = 0; st < 4; ++st) {
            const int t = tbase + st;
            f32x4 c[4];
            if (g == 0 && st == 0) {              // wave-uniform branch
#pragma unroll
                for (int nt = 0; nt < 4; ++nt) {
                    f32x4 z = {init_c[nt], init_c[nt], init_c[nt], init_c[nt]};
                    c[nt] = z;
                }
            } else {
                f32x4 z = {0.0f, 0.0f, 0.0f, 0.0f};
#pragma unroll
                for (int nt = 0; nt < 4; ++nt) {
                    c[nt] = __builtin_amdgcn_mfma_f32_16x16x32_f16(
                        a0, bf[0][nt], z, 0, 0, 0);
                    c[nt] = __builtin_amdgcn_mfma_f32_16x16x32_f16(
                        a1, bf[1][nt], c[nt], 0, 0, 0);
                }
            }

            // pc multiply (p from staged LDS tile) + per-seq partial sums.
            float av[4][4];                       // [nt][j], static indexing
            float pden[4] = {0.0f, 0.0f, 0.0f, 0.0f};
#pragma unroll
            for (int nt = 0; nt < 4; ++nt)
#pragma unroll
                for (int j = 0; j < 4; ++j) {
                    float pcv = (float)pc_base[
                        (st * 16 + grp * 4 + j) * RSTR + nt * 16 + col];
                    float v = c[nt][j] * pcv;
                    av[nt][j] = v;
                    pden[j] += v;
                }

            // Row (16-lane) sums -> den per sequence; normalize + log.
            float r[4];
#pragma unroll
            for (int j = 0; j < 4; ++j) {
                float den = rowsum16(pden[j]);
                if (t >= emit_from) ld[j] += __logf(den);
                r[j] = __builtin_amdgcn_rcpf(den);
            }

            // Transpose: normalized f16 alpha -> ash, then next A-frags.
#pragma unroll
            for (int nt = 0; nt < 4; ++nt)
#pragma unroll
                for (int j = 0; j < 4; ++j)
                    ash[(grp * 4 + j) * RSTR + nt * 16 + col] =
                        (_Float16)(av[nt][j] * r[j]);
            __builtin_amdgcn_wave_barrier();
            a0 = *(const h8*)(ash + col * RSTR + grp * 8);
            a1 = *(const h8*)(ash + col * RSTR + 32 + grp * 8);
            __builtin_amdgcn_wave_barrier();
        }

        XWRITE(cur ^ 1);
        __builtin_amdgcn_wave_barrier();
        cur ^= 1;
    }
#undef XLOAD
#undef XWRITE

    // Final alpha (t=1023 normalized) from ash; f32 out.
    if (seg == NSEG - 1) {
#pragma unroll
        for (int nt = 0; nt < 4; ++nt)
#pragma unroll
            for (int j = 0; j < 4; ++j)
                out_alpha[(size_t)(s0 + grp * 4 + j) * KK + nt * 16 + col] =
                    (float)ash[(grp * 4 + j) * RSTR + nt * 16 + col];
    }
    if (col == 0) {
#pragma unroll
        for (int j = 0; j < 4; ++j)
            seq_logd[seg * SS + s0 + grp * 4 + j] = ld[j];
    }
}

// ---------------------------------------------------------------------------
// nll = -( sum seq_logd + sum mpart )
__global__ __launch_bounds__(256) void finalize(
    const float* __restrict__ seq_logd, const float* __restrict__ mpart,
    float* __restrict__ out_nll)
{
    float v = 0.0f;
    for (int j = threadIdx.x; j < NWAVES; j += 256) v += mpart[j];
    for (int j = threadIdx.x; j < NSEG * SS; j += 256) v += seq_logd[j];
#pragma unroll
    for (int off = 32; off > 0; off >>= 1)
        v += __shfl_xor(v, off, 64);
    __shared__ float sh[4];
    if ((threadIdx.x & 63) == 0) sh[threadIdx.x >> 6] = v;
    __syncthreads();
    if (threadIdx.x == 0) {
        double total = ((double)sh[0] + sh[1]) + ((double)sh[2] + sh[3]);
        out_nll[0] = (float)(-total);
    }
}

extern "C" void kernel_launch(void* const* d_in, const int* in_sizes, int n_in,
                              void* d_out, int out_size, void* d_ws, size_t ws_size,
                              hipStream_t stream) {
    const float* data    = (const float*)d_in[0];  // [T,S,D]
    const float* initial = (const float*)d_in[1];  // [K]
    const float* trans   = (const float*)d_in[2];  // [K,K]
    const float* means   = (const float*)d_in[3];  // [K,D]
    const float* covars  = (const float*)d_in[4];  // [K,D]

    float* out_alpha = (float*)d_out;                    // [S,K]
    float* out_nll   = (float*)d_out + (size_t)SS * KK;  // 1 float

    __half* pbuf     = (__half*)d_ws;
    float*  mpart    = (float*)((char*)d_ws + PBUF_BYTES);
    float*  seq_logd = (float*)((char*)d_ws + PBUF_BYTES + NWAVES * sizeof(float));

    emission_kernel<<<EM_BLOCKS, EM_WPB * 64, 0, stream>>>(
        data, means, covars, pbuf, mpart);
    hmm_mfma<<<dim3(SS / QSEQ, NSEG), 64, 0, stream>>>(
        pbuf, initial, trans, out_alpha, seq_logd);
    finalize<<<1, 256, 0, stream>>>(seq_logd, mpart, out_nll);
}

// Round 13
// 275.090 us; speedup vs baseline: 1.0993x; 1.0455x over previous
//
#include <hip/hip_runtime.h>
#include <hip/hip_fp16.h>
#include <math.h>

// T=1024 time steps, S=512 sequences, D=32 features, K=64 states
#define TT 1024
#define SS 512
#define DD 32
#define KK 64

#define LOG2PI_F 1.8378770664093453f
#define L2E_F    1.4426950408889634f
#define LN2_F    0.6931471805599453f

// MFMA recursion: 16 sequences per wave; NSEG segments. Segments whose
// window start clamps to t0==0 (seg 0..2) use the TRUE initial distribution
// (exact, no approximation); seg>=3 burn in BURN steps from a flat init
// (contraction kills the init error; validated r3-r12 at BURN=64).
// NSEG=32: 1024 waves = 1 per SIMD (was 512 = half the machine idle);
// serial depth 128 -> 96.
#define QSEQ 16
#define NSEG 32
#define SEGLEN (TT / NSEG)   // 32
#define BURN 64

// Workspace layout (d_ws):
//   [0, 64MB)        : p''[T,S,K] fp16 (max-shifted emission probs)
//   [+0, +32KB)      : float mpart[8192]  (log2-domain max sums)
//   [+32KB, +64KB)   : float seq_logd[NSEG*S]
#define PBUF_BYTES ((size_t)TT * SS * KK * 2)
#define EM_WPB 4
#define EM_BLOCKS 2048
#define NWAVES (EM_BLOCKS * EM_WPB)   // 8192 waves, 64 items each = T*S

typedef float v2f __attribute__((ext_vector_type(2)));
typedef float f32x4 __attribute__((ext_vector_type(4)));
typedef _Float16 h8 __attribute__((ext_vector_type(8)));

__device__ __forceinline__ v2f fma2(v2f a, v2f b, v2f c) {
#if __has_builtin(__builtin_elementwise_fma)
    return __builtin_elementwise_fma(a, b, c);
#else
    v2f r; r.x = fmaf(a.x, b.x, c.x); r.y = fmaf(a.y, b.y, c.y); return r;
#endif
}

__device__ __forceinline__ float fast_exp2(float x) {
#if __has_builtin(__builtin_amdgcn_exp2f)
    return __builtin_amdgcn_exp2f(x);       // v_exp_f32 (native base-2)
#else
    return __expf(x * LN2_F);
#endif
}

// ---------------------------------------------------------------------------
// DPP reductions.
template <int CTRL, int RMASK>
__device__ __forceinline__ float dpp_max(float x) {
    int xi = __float_as_int(x);
    int t = __builtin_amdgcn_update_dpp(xi, xi, CTRL, RMASK, 0xf, false);
    return fmaxf(x, __int_as_float(t));
}
__device__ __forceinline__ float wave_reduce_max(float x) {
    x = dpp_max<0x111, 0xf>(x);
    x = dpp_max<0x112, 0xf>(x);
    x = dpp_max<0x114, 0xf>(x);
    x = dpp_max<0x118, 0xf>(x);
    x = dpp_max<0x142, 0xa>(x);
    x = dpp_max<0x143, 0xc>(x);
    return __int_as_float(__builtin_amdgcn_readlane(__float_as_int(x), 63));
}
// 16-lane row sum via row_ror rotate-reduce (all 16 lanes end with the total).
template <int N>
__device__ __forceinline__ float dpp_ror_add(float x) {
    int xi = __float_as_int(x);
    int t = __builtin_amdgcn_update_dpp(xi, xi, 0x120 + N, 0xf, 0xf, false);
    return x + __int_as_float(t);
}
__device__ __forceinline__ float rowsum16(float x) {
    x = dpp_ror_add<8>(x);
    x = dpp_ror_add<4>(x);
    x = dpp_ror_add<2>(x);
    x = dpp_ror_add<1>(x);
    return x;
}

// ---------------------------------------------------------------------------
// Emission: one wave per batch of 64 (t,s) items; lane = state k.
// r9 skeleton (the only shape measured at a healthy 132 VGPR / no remat),
// with two semantic cuts vs r9:
//  - x^2 staged alongside x (computed once per element at staging time):
//    inner loop is 2 pure-FMA chains  logp2 = sum x^2*W + sum x*MW + C
//    (expanded form, ref-checked in r3) — deletes all subtractions.
//  - log2 domain: W = -0.5*l2e/c, MW = l2e*m/c, C = -0.5*l2e*(c0 + sum m^2/c);
//    p'' = exp2(logp2 - mx2) — IDENTICAL value to exp(logp - mx); native
//    v_exp_f32, no ln2 multiply on the chain. mpart carries log2 units
//    (finalize scales by ln2).
__global__ __launch_bounds__(EM_WPB * 64)
__attribute__((amdgpu_waves_per_eu(1, 3)))
void emission_kernel(
    const float* __restrict__ data,      // [T,S,D]
    const float* __restrict__ means,     // [K,D]
    const float* __restrict__ covars,    // [K,D]
    __half* __restrict__ pbuf,           // [T,S,K]
    float* __restrict__ mpart)           // [NWAVES], log2 units
{
    const int k  = threadIdx.x & 63;
    const int w  = threadIdx.x >> 6;
    const int wv = blockIdx.x * EM_WPB + w;

    // Per-lane (state-k) constants: W2/MW2 (64 VGPRs) + C.
    v2f W2[DD / 2], MW2[DD / 2];
    float c0 = DD * LOG2PI_F;
    float mm = 0.0f;
#pragma unroll
    for (int d = 0; d < DD; ++d) {
        float c = covars[k * DD + d];
        float m = means[k * DD + d];
        float wi = 1.0f / c;
        ((float*)W2)[d]  = -0.5f * L2E_F * wi;
        ((float*)MW2)[d] = L2E_F * wi * m;
        mm += m * m * wi;
        c0 += __logf(c);
    }
    const float C = -0.5f * L2E_F * (c0 + mm);

    // x and x^2 staging: per wave, 2 buffers x 8 items x 32 floats each plane.
    __shared__ __align__(16) float4 xst[EM_WPB][2][64];
    __shared__ __align__(16) float4 sst[EM_WPB][2][64];

    const int base = wv * 64;
    const float4* dsrc = (const float4*)(data + (size_t)base * DD);

    float4 xr = dsrc[k];
    float4 sr; sr.x = xr.x * xr.x; sr.y = xr.y * xr.y;
    sr.z = xr.z * xr.z; sr.w = xr.w * xr.w;
    xst[w][0][k] = xr;
    sst[w][0][k] = sr;
    __builtin_amdgcn_wave_barrier();

    float macc = 0.0f;                   // sum of per-item mx2 (log2 units)
    int cur = 0;

    for (int b = 0; b < 8; ++b) {        // 8 blocks of 8 items
        const int bn = (b + 1 < 8) ? (b + 1) : 7;   // uniform, harmless
        xr = dsrc[bn * 64 + k];

        const float* xb = (const float*)&xst[w][cur][0];
        const float* sb = (const float*)&sst[w][cur][0];
#pragma unroll
        for (int i = 0; i < 8; ++i) {
            const int item = base + b * 8 + i;
            const float4* xq = (const float4*)(xb + i * DD);  // broadcast
            const float4* sq = (const float4*)(sb + i * DD);  // broadcast
            v2f qa = {C, 0.0f}, qb = {0.0f, 0.0f};
            v2f qc = {0.0f, 0.0f}, qd = {0.0f, 0.0f};
#pragma unroll
            for (int d4 = 0; d4 < DD / 4; ++d4) {
                float4 xv = xq[d4];
                float4 sv = sq[d4];
                v2f x01; x01.x = xv.x; x01.y = xv.y;
                v2f x23; x23.x = xv.z; x23.y = xv.w;
                v2f s01; s01.x = sv.x; s01.y = sv.y;
                v2f s23; s23.x = sv.z; s23.y = sv.w;
                qa = fma2(s01, W2[2 * d4], qa);
                qb = fma2(s23, W2[2 * d4 + 1], qb);
                qc = fma2(x01, MW2[2 * d4], qc);
                qd = fma2(x23, MW2[2 * d4 + 1], qd);
            }
            v2f s = (qa + qb) + (qc + qd);
            float logp2 = s.x + s.y;
            float mx2 = wave_reduce_max(logp2);    // DPP, wave-uniform
            pbuf[(size_t)item * KK + k] = __float2half(fast_exp2(logp2 - mx2));
            macc += mx2;
        }

        // Write-late: the vmcnt wait lands here with 8 items of slack.
        float4 s2; s2.x = xr.x * xr.x; s2.y = xr.y * xr.y;
        s2.z = xr.z * xr.z; s2.w = xr.w * xr.w;
        xst[w][cur ^ 1][k] = xr;
        sst[w][cur ^ 1][k] = s2;
        __builtin_amdgcn_wave_barrier();
        cur ^= 1;
    }
    if (k == 0) mpart[wv] = macc;
}

// ---------------------------------------------------------------------------
// MFMA forward recursion: one wave = 16 sequences x one segment.
// alpha_new[16 x 64] = alpha[16 x 64] @ A[64 x 64] via 8x mfma_f32_16x16x32_f16,
// pc-multiply, every-step row-normalize, f16 transpose through LDS.
// Layout contracts (r12 HW-verified by passing refcheck):
//  - C/D: col(n) = lane&15, row(m) = (lane>>4)*4 + reg
//  - A: m = lane&15, k = (lane>>4)*8 + elem; B: n = lane&15, same k map.
// Segments: t0 = max(0, emit_from - BURN). t0==0 (seg 0..2) => TRUE initial
// distribution (exact); else flat init + BURN=64 burn-in.
#define RSTR 72   // padded LDS row stride in halfs

__global__ __launch_bounds__(64)
__attribute__((amdgpu_waves_per_eu(1, 1)))
void hmm_mfma(
    const __half* __restrict__ pbuf,     // [T,S,K] f16 max-shifted probs
    const float* __restrict__ initial,   // [K]
    const float* __restrict__ trans,     // [K,K]
    float* __restrict__ out_alpha,       // [S,K]
    float* __restrict__ seq_logd)        // [NSEG*S]
{
    const int lane = threadIdx.x;
    const int col  = lane & 15;
    const int grp  = lane >> 4;
    const int s0   = blockIdx.x * QSEQ;
    const int seg  = blockIdx.y;

    const int emit_from = seg * SEGLEN;
    int t0 = emit_from - BURN; if (t0 < 0) t0 = 0;
    const int nsteps = (emit_from - t0) + SEGLEN;   // 32..96, multiple of 4

    // B fragments: A_hmm[j][k_out] as f16, tile (kc,nt); j = kc*32 + grp*8 + e.
    h8 bf[2][4];
#pragma unroll
    for (int kc = 0; kc < 2; ++kc)
#pragma unroll
        for (int nt = 0; nt < 4; ++nt) {
            h8 v;
#pragma unroll
            for (int e = 0; e < 8; ++e) {
                int j = kc * 32 + grp * 8 + e;
                v[e] = (_Float16)trans[j * KK + nt * 16 + col];
            }
            bf[kc][nt] = v;
        }

    float init_c[4];
#pragma unroll
    for (int nt = 0; nt < 4; ++nt)
        init_c[nt] = (t0 == 0) ? initial[nt * 16 + col] : 1.0f;

    __shared__ __align__(16) _Float16 ash[QSEQ * RSTR];          // 2.3 KB
    __shared__ __align__(16) _Float16 plds[2][4 * QSEQ * RSTR];  // 18.4 KB

    float4 pr[8];
#define XLOAD(TB)                                                             \
    {                                                                         \
        const float4* src = (const float4*)(pbuf +                            \
            (((size_t)((TB) + grp)) * SS + s0 + col) * KK);                   \
        _Pragma("unroll")                                                     \
        for (int e = 0; e < 8; ++e) pr[e] = src[e];                           \
    }
#define XWRITE(BUF)                                                           \
    {                                                                         \
        float4* dst = (float4*)(&plds[BUF][(grp * 16 + col) * RSTR]);         \
        _Pragma("unroll")                                                     \
        for (int e = 0; e < 8; ++e) dst[e] = pr[e];                           \
    }

    XLOAD(t0);
    XWRITE(0);
    __builtin_amdgcn_wave_barrier();

    h8 a0, a1;
    float ld[4] = {0.0f, 0.0f, 0.0f, 0.0f};
    int cur = 0;

    for (int g = 0; g < nsteps / 4; ++g) {
        const int tbase = t0 + 4 * g;
        int tb_next = tbase + 4;
        if (tb_next > TT - 4) tb_next = TT - 4;   // uniform clamp (harmless)
        XLOAD(tb_next);

        const _Float16* pc_base = &plds[cur][0];
#pragma unroll
        for (int st = 0; st < 4; ++st) {
            const int t = tbase + st;
            f32x4 c[4];
            if (g == 0 && st == 0) {              // wave-uniform branch
#pragma unroll
                for (int nt = 0; nt < 4; ++nt) {
                    f32x4 z = {init_c[nt], init_c[nt], init_c[nt], init_c[nt]};
                    c[nt] = z;
                }
            } else {
                f32x4 z = {0.0f, 0.0f, 0.0f, 0.0f};
#pragma unroll
                for (int nt = 0; nt < 4; ++nt) {
                    c[nt] = __builtin_amdgcn_mfma_f32_16x16x32_f16(
                        a0, bf[0][nt], z, 0, 0, 0);
                    c[nt] = __builtin_amdgcn_mfma_f32_16x16x32_f16(
                        a1, bf[1][nt], c[nt], 0, 0, 0);
                }
            }

            float av[4][4];
            float pden[4] = {0.0f, 0.0f, 0.0f, 0.0f};
#pragma unroll
            for (int nt = 0; nt < 4; ++nt)
#pragma unroll
                for (int j = 0; j < 4; ++j) {
                    float pcv = (float)pc_base[
                        (st * 16 + grp * 4 + j) * RSTR + nt * 16 + col];
                    float v = c[nt][j] * pcv;
                    av[nt][j] = v;
                    pden[j] += v;
                }

            float r[4];
#pragma unroll
            for (int j = 0; j < 4; ++j) {
                float den = rowsum16(pden[j]);
                if (t >= emit_from) ld[j] += __logf(den);
                r[j] = __builtin_amdgcn_rcpf(den);
            }

#pragma unroll
            for (int nt = 0; nt < 4; ++nt)
#pragma unroll
                for (int j = 0; j < 4; ++j)
                    ash[(grp * 4 + j) * RSTR + nt * 16 + col] =
                        (_Float16)(av[nt][j] * r[j]);
            __builtin_amdgcn_wave_barrier();
            a0 = *(const h8*)(ash + col * RSTR + grp * 8);
            a1 = *(const h8*)(ash + col * RSTR + 32 + grp * 8);
            __builtin_amdgcn_wave_barrier();
        }

        XWRITE(cur ^ 1);
        __builtin_amdgcn_wave_barrier();
        cur ^= 1;
    }
#undef XLOAD
#undef XWRITE

    if (seg == NSEG - 1) {
#pragma unroll
        for (int nt = 0; nt < 4; ++nt)
#pragma unroll
            for (int j = 0; j < 4; ++j)
                out_alpha[(size_t)(s0 + grp * 4 + j) * KK + nt * 16 + col] =
                    (float)ash[(grp * 4 + j) * RSTR + nt * 16 + col];
    }
    if (col == 0) {
#pragma unroll
        for (int j = 0; j < 4; ++j)
            seq_logd[seg * SS + s0 + grp * 4 + j] = ld[j];
    }
}

// ---------------------------------------------------------------------------
// nll = -( sum seq_logd + ln2 * sum mpart )   (mpart is log2-domain)
__global__ __launch_bounds__(256) void finalize(
    const float* __restrict__ seq_logd, const float* __restrict__ mpart,
    float* __restrict__ out_nll)
{
    float v = 0.0f;
    for (int j = threadIdx.x; j < NWAVES; j += 256) v += mpart[j] * LN2_F;
    for (int j = threadIdx.x; j < NSEG * SS; j += 256) v += seq_logd[j];
#pragma unroll
    for (int off = 32; off > 0; off >>= 1)
        v += __shfl_xor(v, off, 64);
    __shared__ float sh[4];
    if ((threadIdx.x & 63) == 0) sh[threadIdx.x >> 6] = v;
    __syncthreads();
    if (threadIdx.x == 0) {
        double total = ((double)sh[0] + sh[1]) + ((double)sh[2] + sh[3]);
        out_nll[0] = (float)(-total);
    }
}

extern "C" void kernel_launch(void* const* d_in, const int* in_sizes, int n_in,
                              void* d_out, int out_size, void* d_ws, size_t ws_size,
                              hipStream_t stream) {
    const float* data    = (const float*)d_in[0];  // [T,S,D]
    const float* initial = (const float*)d_in[1];  // [K]
    const float* trans   = (const float*)d_in[2];  // [K,K]
    const float* means   = (const float*)d_in[3];  // [K,D]
    const float* covars  = (const float*)d_in[4];  // [K,D]

    float* out_alpha = (float*)d_out;                    // [S,K]
    float* out_nll   = (float*)d_out + (size_t)SS * KK;  // 1 float

    __half* pbuf     = (__half*)d_ws;
    float*  mpart    = (float*)((char*)d_ws + PBUF_BYTES);
    float*  seq_logd = (float*)((char*)d_ws + PBUF_BYTES + NWAVES * sizeof(float));

    emission_kernel<<<EM_BLOCKS, EM_WPB * 64, 0, stream>>>(
        data, means, covars, pbuf, mpart);
    hmm_mfma<<<dim3(SS / QSEQ, NSEG), 64, 0, stream>>>(
        pbuf, initial, trans, out_alpha, seq_logd);
    finalize<<<1, 256, 0, stream>>>(seq_logd, mpart, out_nll);
}